// Round 5
// baseline (568.049 us; speedup 1.0000x reference)
//
#include <hip/hip_runtime.h>
#include <hip/hip_bf16.h>

// CombinedModel R5: fused gather+MFMA-MLP, occupancy-restored.
//   prep_weights (1 block): split W1/W2/W3(pad 16x64) -> bf16 hi/lo planes in ws (28 KB).
//   fused kernel, 256 thr / 128 pts per block:
//     Phase A: gather 8 lanes/pt (4 passes), packed split-bf16 latent -> LDS (18.4 KB).
//     Phase B: per-wave MFMA MLP (2 tiles of 16 pts), weight frags STREAMED from ws
//              (no VGPR-resident weights), h-buffer OVERLAID into the wave's own
//              dead lat region (zero extra LDS). lgkmcnt-only fences.
//   LDS 18.4 KB -> 8 blocks/CU; __launch_bounds__(256,6) -> VGPR<=84 -> ~24 waves/CU.

typedef __attribute__((ext_vector_type(2))) float f32x2;
typedef __attribute__((ext_vector_type(4))) float f32x4;
typedef __attribute__((ext_vector_type(4))) int   i32x4;
typedef __attribute__((ext_vector_type(8))) short s16x8;

#define GRID_W  2048
#define LSTR    36   // latent row stride (dwords); 144 B, 16B-aligned rows
#define PSTR    68   // h-buffer row stride (dwords); 272 B, 16B-aligned rows
#define PTS_BLK 128
#define SEL_HI  0x05040100u
#define SEL_LO  0x07060302u
// s_waitcnt imm: vmcnt(63) expcnt(7) lgkmcnt(0) -- DS-only drain, keep vmem in flight
#define LGKM0   0xC07F

static __device__ __forceinline__ unsigned bits_bf2(__hip_bfloat162 h) {
    union { __hip_bfloat162 b; unsigned u; } cv; cv.b = h; return cv.u;
}
static __device__ __forceinline__ void split2_packed(float v0, float v1, unsigned &p0, unsigned &p1) {
    float2 f; f.x = v0; f.y = v1;
    unsigned hu = bits_bf2(__float22bfloat162_rn(f));
    float2 d;
    d.x = v0 - __uint_as_float(hu << 16);
    d.y = v1 - __uint_as_float(hu & 0xffff0000u);
    unsigned lu = bits_bf2(__float22bfloat162_rn(d));
    p0 = (hu & 0xffffu) | (lu << 16);
    p1 = (hu >> 16) | (lu & 0xffff0000u);
}
static __device__ __forceinline__ void split2_planes(float v0, float v1, unsigned &hi01, unsigned &lo01) {
    float2 f; f.x = v0; f.y = v1;
    unsigned hu = bits_bf2(__float22bfloat162_rn(f));
    float2 d;
    d.x = v0 - __uint_as_float(hu << 16);
    d.y = v1 - __uint_as_float(hu & 0xffff0000u);
    hi01 = hu;
    lo01 = bits_bf2(__float22bfloat162_rn(d));
}
static __device__ __forceinline__ s16x8 unpack8(uint4 q0, uint4 q1, unsigned sel) {
    union { unsigned u[4]; s16x8 v; } r;
    r.u[0] = __builtin_amdgcn_perm(q0.y, q0.x, sel);
    r.u[1] = __builtin_amdgcn_perm(q0.w, q0.z, sel);
    r.u[2] = __builtin_amdgcn_perm(q1.y, q1.x, sel);
    r.u[3] = __builtin_amdgcn_perm(q1.w, q1.z, sel);
    return r.v;
}
static __device__ __forceinline__ void lds_fence() {
    __builtin_amdgcn_wave_barrier();
    __builtin_amdgcn_s_waitcnt(LGKM0);
    __builtin_amdgcn_wave_barrier();
}

// ---------------- prep: split weights into ws planes (R3-proven) ----------------
__global__ __launch_bounds__(256) void prep_weights(
    const float* __restrict__ W1, const float* __restrict__ W2, const float* __restrict__ W3,
    unsigned* __restrict__ w1hi, unsigned* __restrict__ w1lo,
    unsigned* __restrict__ w2hi, unsigned* __restrict__ w2lo,
    unsigned* __restrict__ w3hi, unsigned* __restrict__ w3lo)
{
    int t = threadIdx.x;
    for (int i = t; i < 1024; i += 256) split2_planes(W1[2*i], W1[2*i+1], w1hi[i], w1lo[i]);
    for (int i = t; i < 2048; i += 256) split2_planes(W2[2*i], W2[2*i+1], w2hi[i], w2lo[i]);
    for (int i = t; i < 512;  i += 256) {   // W3 zero-padded to [16][64]
        int e0 = 2*i, e1 = 2*i+1;
        float v0 = (e0 < 192) ? W3[e0] : 0.0f;
        float v1 = (e1 < 192) ? W3[e1] : 0.0f;
        split2_planes(v0, v1, w3hi[i], w3lo[i]);
    }
}

// ---------------- fused: gather + MFMA MLP ----------------
__global__ __launch_bounds__(256, 6) void fused_all(
    const float* __restrict__ x,          // [N,2]
    const float* __restrict__ positions,  // [N_POS,2]
    const int*   __restrict__ nbmap,      // [H,W,4]
    const float* __restrict__ emb,        // [N_POS,32]
    const unsigned* __restrict__ w1hi, const unsigned* __restrict__ w1lo,
    const unsigned* __restrict__ w2hi, const unsigned* __restrict__ w2lo,
    const unsigned* __restrict__ w3hi, const unsigned* __restrict__ w3lo,
    const float* __restrict__ b1,         // [64]
    const float* __restrict__ b2,         // [64]
    const float* __restrict__ b3,         // [3]
    const float* __restrict__ mu,         // [3]
    const float* __restrict__ sd,         // [3]
    float* __restrict__ out,              // [N,3]
    int npts)
{
    const int tid  = threadIdx.x;
    const int w    = tid >> 6;
    const int lid  = tid & 63;
    const int quad = lid >> 4;
    const int m16  = lid & 15;
    const int gbase = blockIdx.x * PTS_BLK;

    __shared__ __align__(16) unsigned lat_lds[PTS_BLK * LSTR];   // 18.4 KB

    // ---- Phase A: gather, 8 lanes per point, 4 passes ----
    {
        const int c = tid & 7;          // channel group: channels 4c..4c+3
        const int pr = tid >> 3;        // point row within pass (0..31)
#pragma unroll 2
        for (int pass = 0; pass < 4; ++pass) {
            const int pt = pass * 32 + pr;
            const int g = gbase + pt;
            if (g < npts) {
                f32x2 xv = ((const f32x2*)x)[g];
                int i0 = (int)xv.x, i1 = (int)xv.y;   // x >= 0: trunc == floor
                float f0 = (float)i0, f1 = (float)i1;
                i32x4 nb = ((const i32x4*)nbmap)[i0 * GRID_W + i1];
                int ids[4] = {nb.x, nb.y, nb.z, nb.w};
                float a0 = 0.f, a1 = 0.f, a2 = 0.f, a3 = 0.f;
#pragma unroll
                for (int k = 0; k < 4; ++k) {
                    f32x2 pp = ((const f32x2*)positions)[ids[k]];
                    float dx = pp.x - f0, dy = pp.y - f1;
                    float dist = sqrtf(dx * dx + dy * dy);
                    f32x4 e = *(const f32x4*)(emb + ids[k] * 32 + c * 4);
                    a0 = fmaf(dist, e.x, a0); a1 = fmaf(dist, e.y, a1);
                    a2 = fmaf(dist, e.z, a2); a3 = fmaf(dist, e.w, a3);
                }
                unsigned p0, p1, p2, p3;
                split2_packed(a0, a1, p0, p1);
                split2_packed(a2, a3, p2, p3);
                uint4 pv; pv.x = p0; pv.y = p1; pv.z = p2; pv.w = p3;
                *(uint4*)(lat_lds + pt * LSTR + c * 4) = pv;
            }
        }
    }
    __syncthreads();

    // ---- Phase B: per-wave MFMA MLP over 2 tiles of 16 points ----
    const int pbase = gbase + w * 32;
    if (pbase >= npts) return;            // npts % 64 == 0 -> wave-granular
    unsigned* hb = lat_lds + (w * 32) * LSTR;   // overlay: wave's own dead lat slab

    // pre-read BOTH tiles' A-frags before overlaying
    s16x8 AH[2], AL[2];
#pragma unroll
    for (int t = 0; t < 2; ++t) {
        const unsigned* ap = lat_lds + (w * 32 + t * 16 + m16) * LSTR + quad * 8;
        uint4 q0 = *(const uint4*)ap;
        uint4 q1 = *(const uint4*)(ap + 4);
        AH[t] = unpack8(q0, q1, SEL_HI);
        AL[t] = unpack8(q0, q1, SEL_LO);
    }
    lds_fence();   // all A-frag reads drained before hbuf writes

    float b1v[4], b2v[4];
#pragma unroll
    for (int nt = 0; nt < 4; ++nt) { b1v[nt] = b1[nt * 16 + m16]; b2v[nt] = b2[nt * 16 + m16]; }
    const int mm = (m16 < 3) ? m16 : 0;
    const float b3m = b3[mm], sdm = sd[mm], mum = mu[mm];

    const s16x8* W1H = (const s16x8*)w1hi; const s16x8* W1L = (const s16x8*)w1lo;
    const s16x8* W2H = (const s16x8*)w2hi; const s16x8* W2L = (const s16x8*)w2lo;
    const s16x8* W3H = (const s16x8*)w3hi; const s16x8* W3L = (const s16x8*)w3lo;

#pragma unroll 1
    for (int t = 0; t < 2; ++t) {
        s16x8 ah = AH[t], al = AL[t];
        // L1: latent[16x32] @ W1^T, split 3-product; W1 frags streamed (L2-hot)
        f32x4 c1[4];
#pragma unroll
        for (int nt = 0; nt < 4; ++nt) {
            int fi = (nt * 16 + m16) * 4 + quad;
            s16x8 wh = W1H[fi], wl = W1L[fi];
            f32x4 c = {0.f, 0.f, 0.f, 0.f};
            c = __builtin_amdgcn_mfma_f32_16x16x32_bf16(ah, wl, c, 0, 0, 0);
            c = __builtin_amdgcn_mfma_f32_16x16x32_bf16(al, wh, c, 0, 0, 0);
            c = __builtin_amdgcn_mfma_f32_16x16x32_bf16(ah, wh, c, 0, 0, 0);
            c1[nt] = c;
        }
        __builtin_amdgcn_wave_barrier();
#pragma unroll
        for (int nt = 0; nt < 4; ++nt)
#pragma unroll
            for (int r = 0; r < 4; r += 2) {
                float v0 = fmaxf(c1[nt][r]     + b1v[nt], 0.f);
                float v1 = fmaxf(c1[nt][r + 1] + b1v[nt], 0.f);
                unsigned p0, p1; split2_packed(v0, v1, p0, p1);
                hb[(quad * 4 + r)     * PSTR + nt * 16 + m16] = p0;
                hb[(quad * 4 + r + 1) * PSTR + nt * 16 + m16] = p1;
            }
        lds_fence();

        // L2: h1[16x64] @ W2^T, split 3-product; W2 frags streamed
        f32x4 c2[4] = {{0.f,0.f,0.f,0.f},{0.f,0.f,0.f,0.f},{0.f,0.f,0.f,0.f},{0.f,0.f,0.f,0.f}};
#pragma unroll
        for (int s = 0; s < 2; ++s) {
            const unsigned* rp = hb + m16 * PSTR + s * 32 + quad * 8;
            uint4 h0 = *(const uint4*)rp;
            uint4 h1 = *(const uint4*)(rp + 4);
            s16x8 a2h = unpack8(h0, h1, SEL_HI);
            s16x8 a2l = unpack8(h0, h1, SEL_LO);
#pragma unroll
            for (int nt = 0; nt < 4; ++nt) {
                int fi = (nt * 16 + m16) * 8 + s * 4 + quad;
                s16x8 wh = W2H[fi], wl = W2L[fi];
                c2[nt] = __builtin_amdgcn_mfma_f32_16x16x32_bf16(a2h, wl, c2[nt], 0, 0, 0);
                c2[nt] = __builtin_amdgcn_mfma_f32_16x16x32_bf16(a2l, wh, c2[nt], 0, 0, 0);
                c2[nt] = __builtin_amdgcn_mfma_f32_16x16x32_bf16(a2h, wh, c2[nt], 0, 0, 0);
            }
        }
        lds_fence();   // h1 reads drained before h2 overwrite
#pragma unroll
        for (int nt = 0; nt < 4; ++nt)
#pragma unroll
            for (int r = 0; r < 4; r += 2) {
                float v0 = fmaxf(c2[nt][r]     + b2v[nt], 0.f);
                float v1 = fmaxf(c2[nt][r + 1] + b2v[nt], 0.f);
                unsigned p0, p1; split2_packed(v0, v1, p0, p1);
                hb[(quad * 4 + r)     * PSTR + nt * 16 + m16] = p0;
                hb[(quad * 4 + r + 1) * PSTR + nt * 16 + m16] = p1;
            }
        lds_fence();

        // L3: h2[16x64] @ W3p^T (rows 0..2 valid, rest zero), split 3-product
        f32x4 c3 = {0.f, 0.f, 0.f, 0.f};
#pragma unroll
        for (int s = 0; s < 2; ++s) {
            const unsigned* rp = hb + m16 * PSTR + s * 32 + quad * 8;
            uint4 h0 = *(const uint4*)rp;
            uint4 h1 = *(const uint4*)(rp + 4);
            s16x8 a3h = unpack8(h0, h1, SEL_HI);
            s16x8 a3l = unpack8(h0, h1, SEL_LO);
            int fi = m16 * 8 + s * 4 + quad;
            s16x8 wh = W3H[fi], wl = W3L[fi];
            c3 = __builtin_amdgcn_mfma_f32_16x16x32_bf16(a3h, wl, c3, 0, 0, 0);
            c3 = __builtin_amdgcn_mfma_f32_16x16x32_bf16(a3l, wh, c3, 0, 0, 0);
            c3 = __builtin_amdgcn_mfma_f32_16x16x32_bf16(a3h, wh, c3, 0, 0, 0);
        }
        lds_fence();   // h2 reads drained before next tile's h1 writes
#pragma unroll
        for (int r = 0; r < 4; ++r) {
            float v = (c3[r] + b3m) * sdm + mum;
            v = fminf(fmaxf(v, 0.f), 1.f);   // finite inputs: no NaN path
            if (m16 < 3) out[(size_t)(pbase + t * 16 + quad * 4 + r) * 3 + m16] = v;
        }
    }
}

extern "C" void kernel_launch(void* const* d_in, const int* in_sizes, int n_in,
                              void* d_out, int out_size, void* d_ws, size_t ws_size,
                              hipStream_t stream) {
    const float* x         = (const float*)d_in[0];
    const float* positions = (const float*)d_in[1];
    const int*   nbmap     = (const int*)d_in[2];
    const float* emb       = (const float*)d_in[3];
    const float* W1        = (const float*)d_in[4];
    const float* b1        = (const float*)d_in[5];
    const float* W2        = (const float*)d_in[6];
    const float* b2        = (const float*)d_in[7];
    const float* W3        = (const float*)d_in[8];
    const float* b3        = (const float*)d_in[9];
    const float* mu        = (const float*)d_in[10];
    const float* sd        = (const float*)d_in[11];
    float* out = (float*)d_out;

    int npts = in_sizes[0] / 2;
    unsigned char* ws = (unsigned char*)d_ws;
    unsigned* w1hi = (unsigned*)(ws);
    unsigned* w1lo = (unsigned*)(ws + 4096);
    unsigned* w2hi = (unsigned*)(ws + 8192);
    unsigned* w2lo = (unsigned*)(ws + 16384);
    unsigned* w3hi = (unsigned*)(ws + 24576);
    unsigned* w3lo = (unsigned*)(ws + 26624);

    prep_weights<<<1, 256, 0, stream>>>(W1, W2, W3, w1hi, w1lo, w2hi, w2lo, w3hi, w3lo);
    int blocks = (npts + PTS_BLK - 1) / PTS_BLK;
    fused_all<<<blocks, 256, 0, stream>>>(x, positions, nbmap, emb,
                                          w1hi, w1lo, w2hi, w2lo, w3hi, w3lo,
                                          b1, b2, b3, mu, sd, out, npts);
}

// Round 6
// 224.706 us; speedup vs baseline: 2.5280x; 2.5280x over previous
//
#include <hip/hip_runtime.h>
#include <hip/hip_bf16.h>

// CombinedModel R6: single persistent-wave kernel, in-wave latency hiding.
//   Each wave owns 32-point chunks (stride = total waves). Cross-chunk pipeline:
//     - chunk c+1's x loads issued at top of chunk c's gather
//     - chunk c+1's nbmap loads issued right before chunk c's MLP (hides under MFMA)
//   Gather is wave-local (wave gathers its own 32 pts) -> NO __syncthreads at all.
//   MLP: A-side split-bf16 (hi/lo), W-side single bf16 -> 2-product MFMA (28/tile),
//   weights VGPR-resident (loaded once per wave from fp32 global, no prep kernel).
//   h-buffer overlaid into the wave's dead lat slab (R5-proven trick).
//   __launch_bounds__(256,2): NO forced register budget (R5 spill post-mortem).

typedef __attribute__((ext_vector_type(2))) float f32x2;
typedef __attribute__((ext_vector_type(4))) float f32x4;
typedef __attribute__((ext_vector_type(4))) int   i32x4;
typedef __attribute__((ext_vector_type(8))) short s16x8;

#define GRID_W  2048
#define LSTR    36   // lat row stride (dwords): 144 B rows, 16B-aligned
#define PSTR    68   // h row stride (dwords): 272 B rows, 16B-aligned
#define SEL_HI  0x05040100u
#define SEL_LO  0x07060302u
#define LGKM0   0xC07F   // s_waitcnt vmcnt(63) expcnt(7) lgkmcnt(0): DS-only drain

static __device__ __forceinline__ unsigned bits_bf2(__hip_bfloat162 h) {
    union { __hip_bfloat162 b; unsigned u; } cv; cv.b = h; return cv.u;
}
// split (v0,v1) into bf16 hi + bf16 lo residual; packed dword_i = hi_i | lo_i<<16
static __device__ __forceinline__ void split2_packed(float v0, float v1, unsigned &p0, unsigned &p1) {
    float2 f; f.x = v0; f.y = v1;
    unsigned hu = bits_bf2(__float22bfloat162_rn(f));
    float2 d;
    d.x = v0 - __uint_as_float(hu << 16);
    d.y = v1 - __uint_as_float(hu & 0xffff0000u);
    unsigned lu = bits_bf2(__float22bfloat162_rn(d));
    p0 = (hu & 0xffffu) | (lu << 16);
    p1 = (hu >> 16) | (lu & 0xffff0000u);
}
static __device__ __forceinline__ s16x8 unpack8(uint4 q0, uint4 q1, unsigned sel) {
    union { unsigned u[4]; s16x8 v; } r;
    r.u[0] = __builtin_amdgcn_perm(q0.y, q0.x, sel);
    r.u[1] = __builtin_amdgcn_perm(q0.w, q0.z, sel);
    r.u[2] = __builtin_amdgcn_perm(q1.y, q1.x, sel);
    r.u[3] = __builtin_amdgcn_perm(q1.w, q1.z, sel);
    return r.v;
}
// single-bf16 weight fragment: 8 consecutive fp32 -> 8 bf16 (rtn)
static __device__ __forceinline__ s16x8 load_wbf(const float* p) {
    f32x4 a = ((const f32x4*)p)[0];
    f32x4 b = ((const f32x4*)p)[1];
    union { unsigned u[4]; s16x8 v; } r;
    float2 f;
    f.x = a.x; f.y = a.y; r.u[0] = bits_bf2(__float22bfloat162_rn(f));
    f.x = a.z; f.y = a.w; r.u[1] = bits_bf2(__float22bfloat162_rn(f));
    f.x = b.x; f.y = b.y; r.u[2] = bits_bf2(__float22bfloat162_rn(f));
    f.x = b.z; f.y = b.w; r.u[3] = bits_bf2(__float22bfloat162_rn(f));
    return r.v;
}
static __device__ __forceinline__ void lds_fence() {
    __builtin_amdgcn_wave_barrier();
    __builtin_amdgcn_s_waitcnt(LGKM0);
    __builtin_amdgcn_wave_barrier();
}

__global__ __launch_bounds__(256, 2) void fused_persistent(
    const float* __restrict__ x,          // [N,2]
    const float* __restrict__ positions,  // [N_POS,2]
    const int*   __restrict__ nbmap,      // [H,W,4]
    const float* __restrict__ emb,        // [N_POS,32]
    const float* __restrict__ W1,         // [64,32]
    const float* __restrict__ b1,         // [64]
    const float* __restrict__ W2,         // [64,64]
    const float* __restrict__ b2,         // [64]
    const float* __restrict__ W3,         // [3,64]
    const float* __restrict__ b3,         // [3]
    const float* __restrict__ mu,         // [3]
    const float* __restrict__ sd,         // [3]
    float* __restrict__ out,              // [N,3]
    int npts)
{
    const int tid  = threadIdx.x;
    const int w    = tid >> 6;
    const int lid  = tid & 63;
    const int quad = lid >> 4;
    const int m16  = lid & 15;
    const int c8   = lid & 7;    // gather: channel group (channels 4*c8 .. 4*c8+3)
    const int pr   = lid >> 3;   // gather: point row within pass (0..7)

    const int nwav = gridDim.x * 4;
    const int wgid = blockIdx.x * 4 + w;
    const int NCH  = (npts + 31) >> 5;
    if (wgid >= NCH) return;     // no block barriers anywhere: safe

    __shared__ __align__(16) unsigned lat_lds[4 * 32 * LSTR];   // 18.4 KB
    unsigned* latw = lat_lds + w * 32 * LSTR;   // wave-private 32-row slab
    unsigned* hb   = latw;                      // h-buffer overlays dead lat slab

    const f32x2* Xv  = (const f32x2*)x;
    const f32x2* Pv  = (const f32x2*)positions;
    const i32x4* NBq = (const i32x4*)nbmap;

    // ---- per-wave weights: A-split/W-single -> single-bf16 B-frags ----
    s16x8 w1f[4];
#pragma unroll
    for (int nt = 0; nt < 4; ++nt)
        w1f[nt] = load_wbf(W1 + (nt * 16 + m16) * 32 + quad * 8);
    s16x8 w2f[2][4];
#pragma unroll
    for (int s = 0; s < 2; ++s)
#pragma unroll
        for (int nt = 0; nt < 4; ++nt)
            w2f[s][nt] = load_wbf(W2 + (nt * 16 + m16) * 64 + s * 32 + quad * 8);
    s16x8 w3f[2];
#pragma unroll
    for (int s = 0; s < 2; ++s) {
        if (m16 < 3) {
            w3f[s] = load_wbf(W3 + m16 * 64 + s * 32 + quad * 8);
        } else {
            s16x8 z = {0, 0, 0, 0, 0, 0, 0, 0};
            w3f[s] = z;
        }
    }
    float b1v[4], b2v[4];
#pragma unroll
    for (int nt = 0; nt < 4; ++nt) { b1v[nt] = b1[nt * 16 + m16]; b2v[nt] = b2[nt * 16 + m16]; }
    const int mm = (m16 < 3) ? m16 : 0;
    const float b3m = b3[mm], sdm = sd[mm], mum = mu[mm];

    // ---- pipeline prologue: x + nbmap for first chunk ----
    f32x2 xv[4], xvn[4];
    i32x4 nb[4], nbn[4];
#pragma unroll
    for (int p = 0; p < 4; ++p) {
        int g = wgid * 32 + p * 8 + pr;
        g = (g < npts) ? g : (npts - 1);
        xv[p] = Xv[g];
    }
#pragma unroll
    for (int p = 0; p < 4; ++p) {
        int i0 = (int)xv[p].x, i1 = (int)xv[p].y;   // x >= 0: trunc == floor
        nb[p] = NBq[i0 * GRID_W + i1];
    }

    for (int c = wgid; c < NCH; c += nwav) {
        const int cn = c + nwav;
        const bool hn = (cn < NCH);

        // issue NEXT chunk's x loads now: ~1500 cyc before they're consumed
        if (hn) {
#pragma unroll
            for (int p = 0; p < 4; ++p) {
                int g = cn * 32 + p * 8 + pr;
                g = (g < npts) ? g : (npts - 1);
                xvn[p] = Xv[g];
            }
        }

        // ---- gather chunk c (nb[] already resident; pos/emb = 1 exposed RT) ----
#pragma unroll
        for (int p = 0; p < 4; ++p) {
            f32x2 xvp = xv[p];
            float f0 = (float)(int)xvp.x, f1 = (float)(int)xvp.y;
            i32x4 n4 = nb[p];
            int ids[4] = {n4.x, n4.y, n4.z, n4.w};
            float a0 = 0.f, a1 = 0.f, a2 = 0.f, a3 = 0.f;
#pragma unroll
            for (int k = 0; k < 4; ++k) {
                f32x2 pp = Pv[ids[k]];
                float dx = pp.x - f0, dy = pp.y - f1;
                float dist = sqrtf(dx * dx + dy * dy);
                f32x4 e = *(const f32x4*)(emb + ids[k] * 32 + c8 * 4); // 8 lanes = full 128B row
                a0 = fmaf(dist, e.x, a0); a1 = fmaf(dist, e.y, a1);
                a2 = fmaf(dist, e.z, a2); a3 = fmaf(dist, e.w, a3);
            }
            unsigned p0, p1, p2, p3;
            split2_packed(a0, a1, p0, p1);
            split2_packed(a2, a3, p2, p3);
            uint4 pv; pv.x = p0; pv.y = p1; pv.z = p2; pv.w = p3;
            *(uint4*)(latw + (p * 8 + pr) * LSTR + c8 * 4) = pv;
        }
        lds_fence();

        // pre-read BOTH tiles' A-frags before hb overlay
        s16x8 AH[2], AL[2];
#pragma unroll
        for (int t = 0; t < 2; ++t) {
            const unsigned* ap = latw + (t * 16 + m16) * LSTR + quad * 8;
            uint4 q0 = *(const uint4*)ap;
            uint4 q1 = *(const uint4*)(ap + 4);
            AH[t] = unpack8(q0, q1, SEL_HI);
            AL[t] = unpack8(q0, q1, SEL_LO);
        }
        lds_fence();

        // issue NEXT chunk's nbmap loads (xvn arrived during gather);
        // their round-trip hides under the MLP below
        if (hn) {
#pragma unroll
            for (int p = 0; p < 4; ++p) {
                int i0 = (int)xvn[p].x, i1 = (int)xvn[p].y;
                nbn[p] = NBq[i0 * GRID_W + i1];
            }
        }

        // ---- MLP: 2 tiles of 16 points ----
#pragma unroll
        for (int t = 0; t < 2; ++t) {
            s16x8 ah = AH[t], al = AL[t];
            // L1: (ah+al) @ W1 -> 8 MFMA
            f32x4 c1[4];
#pragma unroll
            for (int nt = 0; nt < 4; ++nt) {
                f32x4 cc = {0.f, 0.f, 0.f, 0.f};
                cc = __builtin_amdgcn_mfma_f32_16x16x32_bf16(al, w1f[nt], cc, 0, 0, 0);
                cc = __builtin_amdgcn_mfma_f32_16x16x32_bf16(ah, w1f[nt], cc, 0, 0, 0);
                c1[nt] = cc;
            }
            __builtin_amdgcn_wave_barrier();
#pragma unroll
            for (int nt = 0; nt < 4; ++nt)
#pragma unroll
                for (int r = 0; r < 4; r += 2) {
                    float v0 = fmaxf(c1[nt][r]     + b1v[nt], 0.f);
                    float v1 = fmaxf(c1[nt][r + 1] + b1v[nt], 0.f);
                    unsigned p0, p1; split2_packed(v0, v1, p0, p1);
                    hb[(quad * 4 + r)     * PSTR + nt * 16 + m16] = p0;
                    hb[(quad * 4 + r + 1) * PSTR + nt * 16 + m16] = p1;
                }
            lds_fence();

            // L2: (a2h+a2l) @ W2 -> 16 MFMA
            f32x4 c2[4] = {{0.f,0.f,0.f,0.f},{0.f,0.f,0.f,0.f},{0.f,0.f,0.f,0.f},{0.f,0.f,0.f,0.f}};
#pragma unroll
            for (int s = 0; s < 2; ++s) {
                const unsigned* rp = hb + m16 * PSTR + s * 32 + quad * 8;
                uint4 h0 = *(const uint4*)rp;
                uint4 h1 = *(const uint4*)(rp + 4);
                s16x8 a2h = unpack8(h0, h1, SEL_HI);
                s16x8 a2l = unpack8(h0, h1, SEL_LO);
#pragma unroll
                for (int nt = 0; nt < 4; ++nt) {
                    c2[nt] = __builtin_amdgcn_mfma_f32_16x16x32_bf16(a2l, w2f[s][nt], c2[nt], 0, 0, 0);
                    c2[nt] = __builtin_amdgcn_mfma_f32_16x16x32_bf16(a2h, w2f[s][nt], c2[nt], 0, 0, 0);
                }
            }
            lds_fence();   // h1 reads drained before h2 overwrite
#pragma unroll
            for (int nt = 0; nt < 4; ++nt)
#pragma unroll
                for (int r = 0; r < 4; r += 2) {
                    float v0 = fmaxf(c2[nt][r]     + b2v[nt], 0.f);
                    float v1 = fmaxf(c2[nt][r + 1] + b2v[nt], 0.f);
                    unsigned p0, p1; split2_packed(v0, v1, p0, p1);
                    hb[(quad * 4 + r)     * PSTR + nt * 16 + m16] = p0;
                    hb[(quad * 4 + r + 1) * PSTR + nt * 16 + m16] = p1;
                }
            lds_fence();

            // L3: (a3h+a3l) @ W3p -> 4 MFMA (rows 0..2 valid)
            f32x4 c3 = {0.f, 0.f, 0.f, 0.f};
#pragma unroll
            for (int s = 0; s < 2; ++s) {
                const unsigned* rp = hb + m16 * PSTR + s * 32 + quad * 8;
                uint4 h0 = *(const uint4*)rp;
                uint4 h1 = *(const uint4*)(rp + 4);
                s16x8 a3h = unpack8(h0, h1, SEL_HI);
                s16x8 a3l = unpack8(h0, h1, SEL_LO);
                c3 = __builtin_amdgcn_mfma_f32_16x16x32_bf16(a3l, w3f[s], c3, 0, 0, 0);
                c3 = __builtin_amdgcn_mfma_f32_16x16x32_bf16(a3h, w3f[s], c3, 0, 0, 0);
            }
            lds_fence();   // h2 reads drained before next h-writes / next gather
#pragma unroll
            for (int r = 0; r < 4; ++r) {
                float v = (c3[r] + b3m) * sdm + mum;
                v = fminf(fmaxf(v, 0.f), 1.f);   // finite inputs: no NaN path
                int gpt = c * 32 + t * 16 + quad * 4 + r;
                if (m16 < 3 && gpt < npts) out[(size_t)gpt * 3 + m16] = v;
            }
        }

        // rotate pipeline registers
        if (hn) {
#pragma unroll
            for (int p = 0; p < 4; ++p) { xv[p] = xvn[p]; nb[p] = nbn[p]; }
        }
    }
}

extern "C" void kernel_launch(void* const* d_in, const int* in_sizes, int n_in,
                              void* d_out, int out_size, void* d_ws, size_t ws_size,
                              hipStream_t stream) {
    const float* x         = (const float*)d_in[0];
    const float* positions = (const float*)d_in[1];
    const int*   nbmap     = (const int*)d_in[2];
    const float* emb       = (const float*)d_in[3];
    const float* W1        = (const float*)d_in[4];
    const float* b1        = (const float*)d_in[5];
    const float* W2        = (const float*)d_in[6];
    const float* b2        = (const float*)d_in[7];
    const float* W3        = (const float*)d_in[8];
    const float* b3        = (const float*)d_in[9];
    const float* mu        = (const float*)d_in[10];
    const float* sd        = (const float*)d_in[11];
    float* out = (float*)d_out;

    int npts = in_sizes[0] / 2;
    // persistent grid: 4 blocks/CU worth of waves; chunk-stride loop absorbs the rest
    int nch = (npts + 31) / 32;
    int blocks = 1024;
    int maxb = (nch + 3) / 4;
    if (blocks > maxb) blocks = maxb;
    fused_persistent<<<blocks, 256, 0, stream>>>(x, positions, nbmap, emb,
                                                 W1, b1, W2, b2, W3, b3, mu, sd,
                                                 out, npts);
}